// Round 18
// baseline (245.358 us; speedup 1.0000x reference)
//
#include <hip/hip_runtime.h>
#include <stdint.h>

#define B_   8
#define L_   512
#define HID_ 768
#define NH_  12
#define D_   64
#define BH_  96
#define TT_  96   // 32 hop + 64 edge combined bias/bucket width

typedef __attribute__((ext_vector_type(8))) short short8;
typedef __attribute__((ext_vector_type(4))) float fv4;

#define MFMA16(a, b, c) __builtin_amdgcn_mfma_f32_16x16x32_bf16((a), (b), (c), 0, 0, 0)

__device__ __forceinline__ float bf2f(uint16_t h) {
  union { uint32_t u; float f; } c; c.u = ((uint32_t)h) << 16; return c.f;
}
__device__ __forceinline__ uint16_t f2bf(float x) {
  union { float f; uint32_t u; } c; c.f = x;
  uint32_t r = (c.u + 0x7FFFu + ((c.u >> 16) & 1u)) >> 16;
  return (uint16_t)r;
}
__device__ __forceinline__ float clampf(float v, float lim) {
  return fminf(fmaxf(v, -lim), lim);
}

// Async global->LDS 16B/lane (m97 pattern; validated R12).
__device__ __forceinline__ void gld_lds16(const uint16_t* g, uint16_t* lds) {
  __builtin_amdgcn_global_load_lds(
      (const __attribute__((address_space(1))) uint32_t*)(uintptr_t)g,
      (__attribute__((address_space(3))) uint32_t*)(uintptr_t)lds, 16, 0, 0);
}

// Inline dtype detect (R5/R6-validated).
__device__ __forceinline__ int detect_fp32(const void* xraw) {
  const uint16_t* r = (const uint16_t*)xraw;
  int cnt = 0;
#pragma unroll
  for (int j = 0; j < 16; j++) {
    uint16_t u = r[2 * j];
    int e = (u >> 7) & 0xFF;
    if (u != 0 && e >= 100 && e <= 140) cnt++;
  }
  return cnt < 10;
}

// ---------------------------------------------------------------------------
// Segment map for the canonical bf16 input block.
// ---------------------------------------------------------------------------
#define SEG_X    0
#define SEG_QH   3145728
#define SEG_QE   3170304
#define SEG_KH   3219456
#define SEG_KE   3244032
#define SEG_VH   3293184
#define SEG_VE   3317760
#define SEG_BQ   3366912
#define SEG_BK   3367680
#define SEG_BV   3368448
#define SEG_BO   3369216
#define SEG_END  3369984
#define SEG_VET  3369984                   // + NH*D*TT = 73728
#define SEG_ALL  3443712

// Grid partition for the fused prep kernel (R17-validated).
#define PREP_CONV 3363                     // SEG_ALL / 1024 (4 elems/thread)
#define PREP_PK   128
#define PREP_TR   2304
#define PREP_ALL  (PREP_CONV + PREP_PK + PREP_TR)

// ---------------------------------------------------------------------------
// ONE prep dispatch (R17-validated): convert+VET | PK swizzle | transposes.
// ---------------------------------------------------------------------------
__global__ __launch_bounds__(256) void prep_all(
    const void* __restrict__ x, const void* __restrict__ qh,
    const void* __restrict__ qe, const void* __restrict__ kh,
    const void* __restrict__ ke, const void* __restrict__ vh,
    const void* __restrict__ ve, const void* __restrict__ b0,
    const void* __restrict__ b1, const void* __restrict__ b2,
    const void* __restrict__ b3, const void* __restrict__ w0,
    const void* __restrict__ w1, const void* __restrict__ w2,
    const void* __restrict__ w3, const int* __restrict__ hop,
    const int* __restrict__ edge, uint16_t* __restrict__ dst,
    uint16_t* __restrict__ VET, uint16_t* __restrict__ PKs,
    uint16_t* __restrict__ WT) {
  __shared__ union {
    uint16_t tr[32][33];
    uint16_t pk[32][512];
  } sm;
  const int blk = blockIdx.x;
  const int tid = threadIdx.x;

  if (blk < PREP_CONV) {
    const int f = detect_fp32(x);
#pragma unroll
    for (int kk = 0; kk < 4; kk++) {
      const int gid = blk * 1024 + kk * 256 + tid;
      if (gid >= SEG_ALL) break;
      if (gid >= SEG_VET) {
        const int g = gid - SEG_VET;
        const int t = g % TT_;
        const int d = (g / TT_) % D_;
        const int hh = g / (TT_ * D_);
        const void* src = (t < 32) ? vh : ve;
        const size_t idx = (size_t)(t < 32 ? t : t - 32) * HID_ + hh * D_ + d;
        VET[g] =
            f ? f2bf(((const float*)src)[idx]) : ((const uint16_t*)src)[idx];
        continue;
      }
      const void* src;
      int local;
      if (gid < SEG_QH)      { src = x;  local = gid - SEG_X; }
      else if (gid < SEG_QE) { src = qh; local = gid - SEG_QH; }
      else if (gid < SEG_KH) { src = qe; local = gid - SEG_QE; }
      else if (gid < SEG_KE) { src = kh; local = gid - SEG_KH; }
      else if (gid < SEG_VH) { src = ke; local = gid - SEG_KE; }
      else if (gid < SEG_VE) { src = vh; local = gid - SEG_VH; }
      else if (gid < SEG_BQ) { src = ve; local = gid - SEG_VE; }
      else if (gid < SEG_BK) { src = b0; local = gid - SEG_BQ; }
      else if (gid < SEG_BV) { src = b1; local = gid - SEG_BK; }
      else if (gid < SEG_BO) { src = b2; local = gid - SEG_BV; }
      else                   { src = b3; local = gid - SEG_BO; }
      dst[gid] =
          f ? f2bf(((const float*)src)[local]) : ((const uint16_t*)src)[local];
    }
  } else if (blk < PREP_CONV + PREP_PK) {
    const int n = blk - PREP_CONV;
    const int half = n & 1, it = (n >> 1) & 7, b = n >> 4;
    const int gi0 = it * 64 + half * 32;
    const int* hb = hop + ((size_t)b * L_ + gi0) * L_;
    const int* eb = edge + ((size_t)b * L_ + gi0) * L_;
#pragma unroll
    for (int c = 0; c < 16; c++) {
      const int flat4 = (c * 256 + tid) * 4;
      const int row = flat4 >> 9, col = flat4 & 511;
      int4 hv = *(const int4*)&hb[(size_t)row * L_ + col];
      int4 ev = *(const int4*)&eb[(size_t)row * L_ + col];
      ushort4 pk;
      pk.x = (uint16_t)((hv.x & 31) | ((ev.x & 63) << 8));
      pk.y = (uint16_t)((hv.y & 31) | ((ev.y & 63) << 8));
      pk.z = (uint16_t)((hv.z & 31) | ((ev.z & 63) << 8));
      pk.w = (uint16_t)((hv.w & 31) | ((ev.w & 63) << 8));
      *(ushort4*)&sm.pk[row][col] = pk;
    }
    __syncthreads();
    uint16_t* out = PKs + ((size_t)(b * 8 + it) * 4 + half * 2) * 8192;
#pragma unroll
    for (int s = 0; s < 8; s++) {
      const int base = s * 2048 + tid * 8;
      short8 v;
#pragma unroll
      for (int j = 0; j < 8; j++) {
        const int ol = base + j;
        const int wl = ol >> 13;
        const int rem = ol & 8191;
        const int jc = rem >> 10;
        const int lane = (rem >> 4) & 63;
        const int k = rem & 15;
        const int lrow = wl * 16 + (lane >> 4) * 4 + (k >> 2);
        const int col = jc * 64 + (k & 3) * 16 + (lane & 15);
        v[j] = (short)sm.pk[lrow][col];
      }
      *(short8*)&out[base] = v;
    }
  } else {
    const int zz = blk - PREP_CONV - PREP_PK;
    const int z = zz / 576;
    const int tile = zz % 576;
    const int bx = tile % 24, by = tile / 24;
    const void* src = (z == 0) ? w0 : (z == 1) ? w1 : (z == 2) ? w2 : w3;
    uint16_t* dstw = WT + (size_t)z * (768 * 768);
    const int fp32 = detect_fp32(x);
    const int tx = tid & 31, ty = tid >> 5;
    const int r0 = by * 32, c0 = bx * 32;
#pragma unroll
    for (int k = 0; k < 4; k++) {
      size_t idx = (size_t)(r0 + ty + k * 8) * 768 + c0 + tx;
      sm.tr[ty + k * 8][tx] =
          fp32 ? f2bf(((const float*)src)[idx]) : ((const uint16_t*)src)[idx];
    }
    __syncthreads();
#pragma unroll
    for (int k = 0; k < 4; k++)
      dstw[(size_t)(c0 + ty + k * 8) * 768 + r0 + tx] = sm.tr[tx][ty + k * 8];
  }
}

// ---------------------------------------------------------------------------
// 64x128-tile bf16 MFMA GEMM (R18: half-M retile of the validated gemm128;
// grid (64,6,3) = 1152 blocks = 4.5/CU — the old 576-block grid was
// occupancy-limited BY GRID, exposing the staging barriers).
// z0/z1 -> bf16 [B,NH,L,D]; z2 writes V transposed to vt [B,NH,D,L].
// ---------------------------------------------------------------------------
__global__ __launch_bounds__(256) void gemm128(
    const uint16_t* __restrict__ A,
    const uint16_t* __restrict__ BT0, const uint16_t* __restrict__ BT1,
    const uint16_t* __restrict__ BT2,
    const uint16_t* __restrict__ bias0, const uint16_t* __restrict__ bias1,
    const uint16_t* __restrict__ bias2,
    uint16_t* __restrict__ out, uint16_t* __restrict__ vt) {
  const int z = blockIdx.z;
  const uint16_t* BT = (z == 0) ? BT0 : (z == 1) ? BT1 : BT2;
  const uint16_t* bias = (z == 0) ? bias0 : (z == 1) ? bias1 : bias2;

  __shared__ __align__(16) uint16_t As[64 * 32];
  __shared__ __align__(16) uint16_t Bs[128 * 32];

  const int tid = threadIdx.x;
  const int lane = tid & 63, quad = lane >> 4, l16 = lane & 15;
  const int w = tid >> 6, wm = w & 1, wn = w >> 1;
  const int m0 = blockIdx.x * 64, n0 = blockIdx.y * 128;

  fv4 acc[2][4];
#pragma unroll
  for (int i = 0; i < 2; i++)
#pragma unroll
    for (int j = 0; j < 4; j++) acc[i][j] = (fv4){0.f, 0.f, 0.f, 0.f};

  // A: 256 chunks (64 rows x 4 slots), 1/thread. B: 512 chunks, 2/thread.
  const int cA = tid;
  const int rA = cA >> 2, gA = (cA & 3) ^ ((rA >> 1) & 3);
  const int cB0 = tid, cB1 = tid + 256;
  const int rB0 = cB0 >> 2, gB0 = (cB0 & 3) ^ ((rB0 >> 1) & 3);
  const int rB1 = cB1 >> 2, gB1 = (cB1 & 3) ^ ((rB1 >> 1) & 3);
  const uint16_t* Ap = A + (size_t)(m0 + rA) * HID_ + gA * 8;
  const uint16_t* Bp0 = BT + (size_t)(n0 + rB0) * HID_ + gB0 * 8;
  const uint16_t* Bp1 = BT + (size_t)(n0 + rB1) * HID_ + gB1 * 8;
  uint16_t* lA = &As[cA * 8];
  uint16_t* lB0 = &Bs[cB0 * 8];
  uint16_t* lB1 = &Bs[cB1 * 8];

  int aoff[2], boff[4];
#pragma unroll
  for (int mi = 0; mi < 2; mi++) {
    int row = wm * 32 + mi * 16 + l16;
    aoff[mi] = row * 32 + (quad ^ ((row >> 1) & 3)) * 8;
  }
#pragma unroll
  for (int ni = 0; ni < 4; ni++) {
    int row = wn * 64 + ni * 16 + l16;
    boff[ni] = row * 32 + (quad ^ ((row >> 1) & 3)) * 8;
  }

  for (int k0 = 0; k0 < HID_; k0 += 32) {
    __syncthreads();
    gld_lds16(Ap + k0, lA);
    gld_lds16(Bp0 + k0, lB0);
    gld_lds16(Bp1 + k0, lB1);
    __syncthreads();
    short8 af[2], bf[4];
#pragma unroll
    for (int mi = 0; mi < 2; mi++) af[mi] = *(const short8*)&As[aoff[mi]];
#pragma unroll
    for (int ni = 0; ni < 4; ni++) bf[ni] = *(const short8*)&Bs[boff[ni]];
#pragma unroll
    for (int mi = 0; mi < 2; mi++)
#pragma unroll
      for (int ni = 0; ni < 4; ni++)
        acc[mi][ni] = MFMA16(af[mi], bf[ni], acc[mi][ni]);
  }

#pragma unroll
  for (int mi = 0; mi < 2; mi++) {
#pragma unroll
    for (int ni = 0; ni < 4; ni++) {
      const int gn = n0 + wn * 64 + ni * 16 + l16;
      const float bv = bf2f(bias[gn]);
      const int gm0 = m0 + wm * 32 + mi * 16 + quad * 4;
      if (z == 2) {
        const int bb = gm0 >> 9, ll0 = gm0 & 511;
        const int hh = gn >> 6, dd = gn & 63;
        ushort4 pk;
        pk.x = f2bf(clampf(acc[mi][ni][0] + bv, 1e4f));
        pk.y = f2bf(clampf(acc[mi][ni][1] + bv, 1e4f));
        pk.z = f2bf(clampf(acc[mi][ni][2] + bv, 1e4f));
        pk.w = f2bf(clampf(acc[mi][ni][3] + bv, 1e4f));
        *(ushort4*)&vt[(((size_t)(bb * NH_ + hh)) * D_ + dd) * L_ + ll0] = pk;
      } else {
#pragma unroll
        for (int r = 0; r < 4; r++) {
          const int gm = gm0 + r;
          const float fval = clampf(acc[mi][ni][r] + bv, 1e4f);
          uint16_t* O = out + (size_t)z * ((size_t)BH_ * L_ * D_);
          const int bb = gm >> 9, ll = gm & 511, hh = gn >> 6, dd = gn & 63;
          O[(((size_t)(bb * NH_ + hh)) * L_ + ll) * D_ + dd] = f2bf(fval);
        }
      }
    }
  }
}

// ---------------------------------------------------------------------------
// 64x64-tile out-projection GEMM, BK=64, fp32 output (validated R15).
// ---------------------------------------------------------------------------
__global__ __launch_bounds__(256) void gemm64o(
    const uint16_t* __restrict__ A, const uint16_t* __restrict__ BT,
    const uint16_t* __restrict__ bias, float* __restrict__ out) {
  __shared__ __align__(16) uint16_t As[64 * 64];
  __shared__ __align__(16) uint16_t Bs[64 * 64];

  const int tid = threadIdx.x;
  const int lane = tid & 63, quad = lane >> 4, l16 = lane & 15;
  const int w = tid >> 6, wm = w & 1, wn = w >> 1;
  const int m0 = blockIdx.x * 64, n0 = blockIdx.y * 64;

  fv4 acc[2][2];
#pragma unroll
  for (int i = 0; i < 2; i++)
#pragma unroll
    for (int j = 0; j < 2; j++) acc[i][j] = (fv4){0.f, 0.f, 0.f, 0.f};

  const int c0 = tid, c1 = tid + 256;
  const int r0 = c0 >> 3, g0 = (c0 & 7) ^ (r0 & 7);
  const int r1 = c1 >> 3, g1 = (c1 & 7) ^ (r1 & 7);
  const uint16_t* A0 = A + (size_t)(m0 + r0) * HID_ + g0 * 8;
  const uint16_t* A1 = A + (size_t)(m0 + r1) * HID_ + g1 * 8;
  const uint16_t* B0 = BT + (size_t)(n0 + r0) * HID_ + g0 * 8;
  const uint16_t* B1 = BT + (size_t)(n0 + r1) * HID_ + g1 * 8;
  uint16_t* lA0 = &As[c0 * 8];
  uint16_t* lA1 = &As[c1 * 8];
  uint16_t* lB0 = &Bs[c0 * 8];
  uint16_t* lB1 = &Bs[c1 * 8];

  int aoff[2][2], boff[2][2];
#pragma unroll
  for (int mi = 0; mi < 2; mi++) {
    const int row = wm * 32 + mi * 16 + l16;
#pragma unroll
    for (int kc = 0; kc < 2; kc++)
      aoff[mi][kc] = row * 64 + ((kc * 4 + quad) ^ (row & 7)) * 8;
  }
#pragma unroll
  for (int ni = 0; ni < 2; ni++) {
    const int row = wn * 32 + ni * 16 + l16;
#pragma unroll
    for (int kc = 0; kc < 2; kc++)
      boff[ni][kc] = row * 64 + ((kc * 4 + quad) ^ (row & 7)) * 8;
  }

  for (int k0 = 0; k0 < HID_; k0 += 64) {
    __syncthreads();
    gld_lds16(A0 + k0, lA0);
    gld_lds16(A1 + k0, lA1);
    gld_lds16(B0 + k0, lB0);
    gld_lds16(B1 + k0, lB1);
    __syncthreads();
#pragma unroll
    for (int kc = 0; kc < 2; kc++) {
      short8 af[2], bf[2];
#pragma unroll
      for (int mi = 0; mi < 2; mi++) af[mi] = *(const short8*)&As[aoff[mi][kc]];
#pragma unroll
      for (int ni = 0; ni < 2; ni++) bf[ni] = *(const short8*)&Bs[boff[ni][kc]];
#pragma unroll
      for (int mi = 0; mi < 2; mi++)
#pragma unroll
        for (int ni = 0; ni < 2; ni++)
          acc[mi][ni] = MFMA16(af[mi], bf[ni], acc[mi][ni]);
    }
  }

#pragma unroll
  for (int mi = 0; mi < 2; mi++) {
#pragma unroll
    for (int ni = 0; ni < 2; ni++) {
      const int gn = n0 + wn * 32 + ni * 16 + l16;
      const float bv = bf2f(bias[gn]);
#pragma unroll
      for (int r = 0; r < 4; r++) {
        const int gm = m0 + wm * 32 + mi * 16 + quad * 4 + r;
        out[(size_t)gm * HID_ + gn] = clampf(acc[mi][ni][r] + bv, 1e4f);
      }
    }
  }
}

// ---------------------------------------------------------------------------
// Fused attention v10.1 (R15-R17-validated; prefetch now guarded jc<7 so the
// wasted wrap-around reload is gone).
// ---------------------------------------------------------------------------
#define SCALE_FX 4194304.f       // 2^22
#define INV_SCALE_FX 2.38418579e-7f
#define UBC 40.f                 // QK upper-bound margin

__global__ __launch_bounds__(256, 3) void attn_kernel(
    const uint16_t* __restrict__ Q, const uint16_t* __restrict__ Km,
    const uint16_t* __restrict__ Vt,
    const uint16_t* __restrict__ qh, const uint16_t* __restrict__ qe,
    const uint16_t* __restrict__ kh, const uint16_t* __restrict__ ke,
    const uint16_t* __restrict__ VET, const uint16_t* __restrict__ PKs,
    uint16_t* __restrict__ AO) {
  const int n = blockIdx.x;
  const int h = n % NH_;
  const int t2 = n / NH_;
  const int it = t2 & 7, b = t2 >> 3;
  const int bh = b * NH_ + h;
  const int tid = threadIdx.x;
  const int w = tid >> 6, lane = tid & 63, quad = lane >> 4, l16 = lane & 15;
  const int gi = it * 64 + w * 16;  // this wave's first query row

  __shared__ uint16_t cbs[4][16][98];               // bf16 bias projections
  __shared__ unsigned bkt[4][16][97];               // fixed-point buckets
  __shared__ __align__(16) uint16_t Pw[4][16][72];  // bf16 P chunk

  for (int k = lane; k < 16 * 97; k += 64)
    (&bkt[0][0][0])[w * 16 * 97 + k] = 0u;

  const size_t qkb = (size_t)bh * (L_ * D_);
  short8 a0 = *(const short8*)&Q[qkb + (size_t)(gi + l16) * D_ + quad * 8];
  short8 a1 = *(const short8*)&Q[qkb + (size_t)(gi + l16) * D_ + 32 + quad * 8];
  short8 kq0 = *(const short8*)&Km[qkb + (size_t)(gi + l16) * D_ + quad * 8];
  short8 kq1 =
      *(const short8*)&Km[qkb + (size_t)(gi + l16) * D_ + 32 + quad * 8];

  // ---- Cb via MFMA (R6-validated); per-row hop/edge maxes for free ----
  float hx[4] = {-1e30f, -1e30f, -1e30f, -1e30f};
  float ex[4] = {-1e30f, -1e30f, -1e30f, -1e30f};
#pragma unroll
  for (int nt = 0; nt < 6; nt++) {
    const uint16_t* eq;
    const uint16_t* ek;
    int t;
    if (nt < 2) { eq = qh; ek = kh; t = nt * 16 + l16; }
    else        { eq = qe; ek = ke; t = (nt - 2) * 16 + l16; }
    const size_t eb0 = (size_t)t * HID_ + h * D_;
    short8 bq0 = *(const short8*)&eq[eb0 + quad * 8];
    short8 bq1 = *(const short8*)&eq[eb0 + 32 + quad * 8];
    short8 bk0 = *(const short8*)&ek[eb0 + quad * 8];
    short8 bk1 = *(const short8*)&ek[eb0 + 32 + quad * 8];
    fv4 cc = (fv4){0.f, 0.f, 0.f, 0.f};
    cc = MFMA16(a0, bq0, cc);
    cc = MFMA16(a1, bq1, cc);
    cc = MFMA16(kq0, bk0, cc);
    cc = MFMA16(kq1, bk1, cc);
#pragma unroll
    for (int r = 0; r < 4; r++) {
      const float cv = clampf(cc[r], 1e4f);
      cbs[w][quad * 4 + r][nt * 16 + l16] = f2bf(cv);
      if (nt < 2) hx[r] = fmaxf(hx[r], cv);
      else        ex[r] = fmaxf(ex[r], cv);
    }
  }

  // UB per row: hop and edge maxes reduced separately, then added.
  float mx[4];
#pragma unroll
  for (int r = 0; r < 4; r++) {
    float mh = hx[r], me = ex[r];
    mh = fmaxf(mh, __shfl_xor(mh, 1, 16));
    mh = fmaxf(mh, __shfl_xor(mh, 2, 16));
    mh = fmaxf(mh, __shfl_xor(mh, 4, 16));
    mh = fmaxf(mh, __shfl_xor(mh, 8, 16));
    me = fmaxf(me, __shfl_xor(me, 1, 16));
    me = fmaxf(me, __shfl_xor(me, 2, 16));
    me = fmaxf(me, __shfl_xor(me, 4, 16));
    me = fmaxf(me, __shfl_xor(me, 8, 16));
    mx[r] = mh + me + UBC;
  }

  const uint16_t* pkw =
      PKs + (((size_t)(b * 8 + it) * 4 + w) * 8) * (64 * 16);
  const size_t vtb = (size_t)bh * (D_ * L_);

  fv4 oacc[4];
#pragma unroll
  for (int ni = 0; ni < 4; ni++) oacc[ni] = (fv4){0.f, 0.f, 0.f, 0.f};
  float lsr[4] = {0.f, 0.f, 0.f, 0.f};

  // preload jc=0 K-fragments + idx
  short8 ckb0[4], ckb1[4];
#pragma unroll
  for (int ni = 0; ni < 4; ni++) {
    const int key = ni * 16 + l16;
    ckb0[ni] = *(const short8*)&Km[qkb + (size_t)key * D_ + quad * 8];
    ckb1[ni] = *(const short8*)&Km[qkb + (size_t)key * D_ + 32 + quad * 8];
  }
  short8 cpk0 = *(const short8*)&pkw[lane * 16];
  short8 cpk1 = *(const short8*)&pkw[lane * 16 + 8];

  for (int jc = 0; jc < 8; jc++) {
    short8 nkb0[4], nkb1[4], npk0, npk1;
    if (jc < 7) {
      const int jn = jc + 1;
#pragma unroll
      for (int ni = 0; ni < 4; ni++) {
        const int key = jn * 64 + ni * 16 + l16;
        nkb0[ni] = *(const short8*)&Km[qkb + (size_t)key * D_ + quad * 8];
        nkb1[ni] = *(const short8*)&Km[qkb + (size_t)key * D_ + 32 + quad * 8];
      }
      npk0 = *(const short8*)&pkw[jn * 1024 + lane * 16];
      npk1 = *(const short8*)&pkw[jn * 1024 + lane * 16 + 8];
    }

    fv4 sacc[4];
#pragma unroll
    for (int ni = 0; ni < 4; ni++) {
      fv4 a = (fv4){0.f, 0.f, 0.f, 0.f};
      a = MFMA16(a0, ckb0[ni], a);
      sacc[ni] = MFMA16(a1, ckb1[ni], a);
    }

    int thv[16], tev[16];
#pragma unroll
    for (int k = 0; k < 16; k++) {
      const uint32_t pk = (uint16_t)((k < 8) ? cpk0[k] : cpk1[k - 8]);
      thv[k] = pk & 31;
      tev[k] = (pk >> 8) & 63;
    }
    float bsum[16];
#pragma unroll
    for (int k = 0; k < 16; k++) {
      const int row = quad * 4 + (k >> 2);
      bsum[k] = bf2f(cbs[w][row][thv[k]]) + bf2f(cbs[w][row][32 + tev[k]]);
    }
    float pv[16];
#pragma unroll
    for (int k = 0; k < 16; k++) {
      const int r = k >> 2;
      const float s = sacc[k & 3][r] + bsum[k];
      const float p = __expf((s - mx[r]) * 0.125f);
      pv[k] = p;
      lsr[r] += p;
    }
#pragma unroll
    for (int k = 0; k < 16; k++) {
      const int row = quad * 4 + (k >> 2);
      const unsigned pfx = (unsigned)(pv[k] * SCALE_FX + 0.5f);
      atomicAdd(&bkt[w][row][thv[k]], pfx);
      atomicAdd(&bkt[w][row][32 + tev[k]], pfx);
      Pw[w][row][(k & 3) * 16 + l16] = f2bf(pv[k]);
    }

#pragma unroll
    for (int kc = 0; kc < 2; kc++) {
      short8 pa = *(const short8*)&Pw[w][l16][kc * 32 + quad * 8];
#pragma unroll
      for (int ni = 0; ni < 4; ni++) {
        short8 vb = *(const short8*)&Vt[vtb + (size_t)(ni * 16 + l16) * L_ +
                                        jc * 64 + kc * 32 + quad * 8];
        oacc[ni] = MFMA16(pa, vb, oacc[ni]);
      }
    }

    if (jc < 7) {
#pragma unroll
      for (int ni = 0; ni < 4; ni++) {
        ckb0[ni] = nkb0[ni];
        ckb1[ni] = nkb1[ni];
      }
      cpk0 = npk0;
      cpk1 = npk1;
    }
  }

  // ---- E = bkt x VET (same C-layout as oacc; R9-R17-validated) ----
  const uint16_t* vet = VET + (size_t)h * D_ * TT_;
#pragma unroll
  for (int kc = 0; kc < 3; kc++) {
    short8 pa;
#pragma unroll
    for (int j = 0; j < 8; j++)
      pa[j] = (short)f2bf((float)bkt[w][l16][kc * 32 + quad * 8 + j] *
                          INV_SCALE_FX);
#pragma unroll
    for (int ni = 0; ni < 4; ni++) {
      short8 vb =
          *(const short8*)&vet[(size_t)(ni * 16 + l16) * TT_ + kc * 32 +
                               quad * 8];
      oacc[ni] = MFMA16(pa, vb, oacc[ni]);
    }
  }

  // ---- register l-normalize ----
  float linv[4];
#pragma unroll
  for (int r = 0; r < 4; r++) {
    float s = lsr[r];
    s += __shfl_xor(s, 1, 16);
    s += __shfl_xor(s, 2, 16);
    s += __shfl_xor(s, 4, 16);
    s += __shfl_xor(s, 8, 16);
    linv[r] = 1.f / s;
  }

#pragma unroll
  for (int ni = 0; ni < 4; ni++)
#pragma unroll
    for (int r = 0; r < 4; r++) {
      const int i = gi + quad * 4 + r;
      AO[(((size_t)b * L_ + i) * NH_ + h) * D_ + ni * 16 + l16] =
          f2bf(oacc[ni][r] * linv[r]);
    }
}

// ---------------------------------------------------------------------------
extern "C" void kernel_launch(void* const* d_in, const int* in_sizes, int n_in,
                              void* d_out, int out_size, void* d_ws,
                              size_t ws_size, hipStream_t stream) {
  const void* x_raw = d_in[0];
  const int* hop    = (const int*)d_in[7];
  const int* edge   = (const int*)d_in[8];

  char* ws = (char*)d_ws;
  uint16_t* QKV = (uint16_t*)(ws);                    // Q,K bf16 [B,NH,L,D]
  uint16_t* Qp  = QKV;
  uint16_t* Kp  = QKV + (size_t)BH_ * L_ * D_;
  uint16_t* Vtp = (uint16_t*)(ws + 18874368);         // [B,NH,D,L] bf16
  uint16_t* PKs = (uint16_t*)(ws + 25165824);         // swizzled idx u16
  uint16_t* AO  = (uint16_t*)(ws + 44040192);         // [B,L,NH,D] bf16
  uint16_t* WTq = (uint16_t*)(ws + 50331648);
  uint16_t* WTk = WTq + 768 * 768;
  uint16_t* WTv = WTk + 768 * 768;
  uint16_t* WTo = WTv + 768 * 768;
  uint16_t* CAN = (uint16_t*)(ws + 55050240);         // canonical bf16 inputs
  uint16_t* VET = (uint16_t*)(ws + 61790208);         // [NH,D,96] bf16

  uint16_t* xc  = CAN + SEG_X;
  uint16_t* qhc = CAN + SEG_QH;
  uint16_t* qec = CAN + SEG_QE;
  uint16_t* khc = CAN + SEG_KH;
  uint16_t* kec = CAN + SEG_KE;
  uint16_t* bqc = CAN + SEG_BQ;
  uint16_t* bkc = CAN + SEG_BK;
  uint16_t* bvc = CAN + SEG_BV;
  uint16_t* boc = CAN + SEG_BO;

  prep_all<<<PREP_ALL, 256, 0, stream>>>(
      x_raw, d_in[1], d_in[2], d_in[3], d_in[4], d_in[5], d_in[6],
      d_in[10], d_in[12], d_in[14], d_in[16],
      d_in[9], d_in[11], d_in[13], d_in[15],
      hop, edge, CAN, VET, PKs, WTq);

  gemm128<<<dim3(64, 6, 3), 256, 0, stream>>>(xc, WTq, WTk, WTv, bqc, bkc,
                                              bvc, QKV, Vtp);

  attn_kernel<<<768, 256, 0, stream>>>(Qp, Kp, Vtp, qhc, qec, khc, kec, VET,
                                       PKs, AO);

  gemm64o<<<dim3(64, 12), 256, 0, stream>>>(AO, WTo, boc, (float*)d_out);
}

// Round 19
// 238.236 us; speedup vs baseline: 1.0299x; 1.0299x over previous
//
#include <hip/hip_runtime.h>
#include <stdint.h>

#define B_   8
#define L_   512
#define HID_ 768
#define NH_  12
#define D_   64
#define BH_  96
#define TT_  96   // 32 hop + 64 edge combined bias/bucket width

typedef __attribute__((ext_vector_type(8))) short short8;
typedef __attribute__((ext_vector_type(4))) float fv4;

#define MFMA16(a, b, c) __builtin_amdgcn_mfma_f32_16x16x32_bf16((a), (b), (c), 0, 0, 0)

__device__ __forceinline__ float bf2f(uint16_t h) {
  union { uint32_t u; float f; } c; c.u = ((uint32_t)h) << 16; return c.f;
}
__device__ __forceinline__ uint16_t f2bf(float x) {
  union { float f; uint32_t u; } c; c.f = x;
  uint32_t r = (c.u + 0x7FFFu + ((c.u >> 16) & 1u)) >> 16;
  return (uint16_t)r;
}
__device__ __forceinline__ float clampf(float v, float lim) {
  return fminf(fmaxf(v, -lim), lim);
}

// Async global->LDS 16B/lane (m97 pattern; validated R12).
__device__ __forceinline__ void gld_lds16(const uint16_t* g, uint16_t* lds) {
  __builtin_amdgcn_global_load_lds(
      (const __attribute__((address_space(1))) uint32_t*)(uintptr_t)g,
      (__attribute__((address_space(3))) uint32_t*)(uintptr_t)lds, 16, 0, 0);
}

// Inline dtype detect (R5/R6-validated).
__device__ __forceinline__ int detect_fp32(const void* xraw) {
  const uint16_t* r = (const uint16_t*)xraw;
  int cnt = 0;
#pragma unroll
  for (int j = 0; j < 16; j++) {
    uint16_t u = r[2 * j];
    int e = (u >> 7) & 0xFF;
    if (u != 0 && e >= 100 && e <= 140) cnt++;
  }
  return cnt < 10;
}

// ---------------------------------------------------------------------------
// Segment map for the canonical bf16 input block.
// ---------------------------------------------------------------------------
#define SEG_X    0
#define SEG_QH   3145728
#define SEG_QE   3170304
#define SEG_KH   3219456
#define SEG_KE   3244032
#define SEG_VH   3293184
#define SEG_VE   3317760
#define SEG_BQ   3366912
#define SEG_BK   3367680
#define SEG_BV   3368448
#define SEG_BO   3369216
#define SEG_END  3369984
#define SEG_VET  3369984                   // + NH*D*TT = 73728
#define SEG_ALL  3443712

// Grid partition for the fused prep kernel (R17-validated).
#define PREP_CONV 3363                     // SEG_ALL / 1024 (4 elems/thread)
#define PREP_PK   128
#define PREP_TR   2304
#define PREP_ALL  (PREP_CONV + PREP_PK + PREP_TR)

// ---------------------------------------------------------------------------
// ONE prep dispatch (R17-validated): convert+VET | PK swizzle | transposes.
// ---------------------------------------------------------------------------
__global__ __launch_bounds__(256) void prep_all(
    const void* __restrict__ x, const void* __restrict__ qh,
    const void* __restrict__ qe, const void* __restrict__ kh,
    const void* __restrict__ ke, const void* __restrict__ vh,
    const void* __restrict__ ve, const void* __restrict__ b0,
    const void* __restrict__ b1, const void* __restrict__ b2,
    const void* __restrict__ b3, const void* __restrict__ w0,
    const void* __restrict__ w1, const void* __restrict__ w2,
    const void* __restrict__ w3, const int* __restrict__ hop,
    const int* __restrict__ edge, uint16_t* __restrict__ dst,
    uint16_t* __restrict__ VET, uint16_t* __restrict__ PKs,
    uint16_t* __restrict__ WT) {
  __shared__ union {
    uint16_t tr[32][33];
    uint16_t pk[32][512];
  } sm;
  const int blk = blockIdx.x;
  const int tid = threadIdx.x;

  if (blk < PREP_CONV) {
    const int f = detect_fp32(x);
#pragma unroll
    for (int kk = 0; kk < 4; kk++) {
      const int gid = blk * 1024 + kk * 256 + tid;
      if (gid >= SEG_ALL) break;
      if (gid >= SEG_VET) {
        const int g = gid - SEG_VET;
        const int t = g % TT_;
        const int d = (g / TT_) % D_;
        const int hh = g / (TT_ * D_);
        const void* src = (t < 32) ? vh : ve;
        const size_t idx = (size_t)(t < 32 ? t : t - 32) * HID_ + hh * D_ + d;
        VET[g] =
            f ? f2bf(((const float*)src)[idx]) : ((const uint16_t*)src)[idx];
        continue;
      }
      const void* src;
      int local;
      if (gid < SEG_QH)      { src = x;  local = gid - SEG_X; }
      else if (gid < SEG_QE) { src = qh; local = gid - SEG_QH; }
      else if (gid < SEG_KH) { src = qe; local = gid - SEG_QE; }
      else if (gid < SEG_KE) { src = kh; local = gid - SEG_KH; }
      else if (gid < SEG_VH) { src = ke; local = gid - SEG_KE; }
      else if (gid < SEG_VE) { src = vh; local = gid - SEG_VH; }
      else if (gid < SEG_BQ) { src = ve; local = gid - SEG_VE; }
      else if (gid < SEG_BK) { src = b0; local = gid - SEG_BQ; }
      else if (gid < SEG_BV) { src = b1; local = gid - SEG_BK; }
      else if (gid < SEG_BO) { src = b2; local = gid - SEG_BV; }
      else                   { src = b3; local = gid - SEG_BO; }
      dst[gid] =
          f ? f2bf(((const float*)src)[local]) : ((const uint16_t*)src)[local];
    }
  } else if (blk < PREP_CONV + PREP_PK) {
    const int n = blk - PREP_CONV;
    const int half = n & 1, it = (n >> 1) & 7, b = n >> 4;
    const int gi0 = it * 64 + half * 32;
    const int* hb = hop + ((size_t)b * L_ + gi0) * L_;
    const int* eb = edge + ((size_t)b * L_ + gi0) * L_;
#pragma unroll
    for (int c = 0; c < 16; c++) {
      const int flat4 = (c * 256 + tid) * 4;
      const int row = flat4 >> 9, col = flat4 & 511;
      int4 hv = *(const int4*)&hb[(size_t)row * L_ + col];
      int4 ev = *(const int4*)&eb[(size_t)row * L_ + col];
      ushort4 pk;
      pk.x = (uint16_t)((hv.x & 31) | ((ev.x & 63) << 8));
      pk.y = (uint16_t)((hv.y & 31) | ((ev.y & 63) << 8));
      pk.z = (uint16_t)((hv.z & 31) | ((ev.z & 63) << 8));
      pk.w = (uint16_t)((hv.w & 31) | ((ev.w & 63) << 8));
      *(ushort4*)&sm.pk[row][col] = pk;
    }
    __syncthreads();
    uint16_t* out = PKs + ((size_t)(b * 8 + it) * 4 + half * 2) * 8192;
#pragma unroll
    for (int s = 0; s < 8; s++) {
      const int base = s * 2048 + tid * 8;
      short8 v;
#pragma unroll
      for (int j = 0; j < 8; j++) {
        const int ol = base + j;
        const int wl = ol >> 13;
        const int rem = ol & 8191;
        const int jc = rem >> 10;
        const int lane = (rem >> 4) & 63;
        const int k = rem & 15;
        const int lrow = wl * 16 + (lane >> 4) * 4 + (k >> 2);
        const int col = jc * 64 + (k & 3) * 16 + (lane & 15);
        v[j] = (short)sm.pk[lrow][col];
      }
      *(short8*)&out[base] = v;
    }
  } else {
    const int zz = blk - PREP_CONV - PREP_PK;
    const int z = zz / 576;
    const int tile = zz % 576;
    const int bx = tile % 24, by = tile / 24;
    const void* src = (z == 0) ? w0 : (z == 1) ? w1 : (z == 2) ? w2 : w3;
    uint16_t* dstw = WT + (size_t)z * (768 * 768);
    const int fp32 = detect_fp32(x);
    const int tx = tid & 31, ty = tid >> 5;
    const int r0 = by * 32, c0 = bx * 32;
#pragma unroll
    for (int k = 0; k < 4; k++) {
      size_t idx = (size_t)(r0 + ty + k * 8) * 768 + c0 + tx;
      sm.tr[ty + k * 8][tx] =
          fp32 ? f2bf(((const float*)src)[idx]) : ((const uint16_t*)src)[idx];
    }
    __syncthreads();
#pragma unroll
    for (int k = 0; k < 4; k++)
      dstw[(size_t)(c0 + ty + k * 8) * 768 + r0 + tx] = sm.tr[tx][ty + k * 8];
  }
}

// ---------------------------------------------------------------------------
// 128x128 bf16 MFMA GEMM (R17-validated tile/grid — R18's 64x128 retile
// doubled B re-fetch and regressed; reverted).
// z0/z1 -> bf16 [B,NH,L,D]; z2 writes V transposed to vt [B,NH,D,L].
// ---------------------------------------------------------------------------
__global__ __launch_bounds__(256) void gemm128(
    const uint16_t* __restrict__ A,
    const uint16_t* __restrict__ BT0, const uint16_t* __restrict__ BT1,
    const uint16_t* __restrict__ BT2,
    const uint16_t* __restrict__ bias0, const uint16_t* __restrict__ bias1,
    const uint16_t* __restrict__ bias2,
    uint16_t* __restrict__ out, uint16_t* __restrict__ vt) {
  const int z = blockIdx.z;
  const uint16_t* BT = (z == 0) ? BT0 : (z == 1) ? BT1 : BT2;
  const uint16_t* bias = (z == 0) ? bias0 : (z == 1) ? bias1 : bias2;

  __shared__ __align__(16) uint16_t As[128 * 32];
  __shared__ __align__(16) uint16_t Bs[128 * 32];

  const int tid = threadIdx.x;
  const int lane = tid & 63, quad = lane >> 4, l16 = lane & 15;
  const int w = tid >> 6, wm = w & 1, wn = w >> 1;
  const int m0 = blockIdx.x * 128, n0 = blockIdx.y * 128;

  fv4 acc[4][4];
#pragma unroll
  for (int i = 0; i < 4; i++)
#pragma unroll
    for (int j = 0; j < 4; j++) acc[i][j] = (fv4){0.f, 0.f, 0.f, 0.f};

  const int c0 = tid, c1 = tid + 256;
  const int r0 = c0 >> 2, g0 = (c0 & 3) ^ ((r0 >> 1) & 3);
  const int r1 = c1 >> 2, g1 = (c1 & 3) ^ ((r1 >> 1) & 3);
  const uint16_t* A0 = A + (size_t)(m0 + r0) * HID_ + g0 * 8;
  const uint16_t* A1 = A + (size_t)(m0 + r1) * HID_ + g1 * 8;
  const uint16_t* B0 = BT + (size_t)(n0 + r0) * HID_ + g0 * 8;
  const uint16_t* B1 = BT + (size_t)(n0 + r1) * HID_ + g1 * 8;
  uint16_t* lA0 = &As[c0 * 8];
  uint16_t* lA1 = &As[c1 * 8];
  uint16_t* lB0 = &Bs[c0 * 8];
  uint16_t* lB1 = &Bs[c1 * 8];

  int aoff[4], boff[4];
#pragma unroll
  for (int mi = 0; mi < 4; mi++) {
    int row = wm * 64 + mi * 16 + l16;
    aoff[mi] = row * 32 + (quad ^ ((row >> 1) & 3)) * 8;
  }
#pragma unroll
  for (int ni = 0; ni < 4; ni++) {
    int row = wn * 64 + ni * 16 + l16;
    boff[ni] = row * 32 + (quad ^ ((row >> 1) & 3)) * 8;
  }

  for (int k0 = 0; k0 < HID_; k0 += 32) {
    __syncthreads();
    gld_lds16(A0 + k0, lA0);
    gld_lds16(A1 + k0, lA1);
    gld_lds16(B0 + k0, lB0);
    gld_lds16(B1 + k0, lB1);
    __syncthreads();
    short8 af[4], bf[4];
#pragma unroll
    for (int mi = 0; mi < 4; mi++) af[mi] = *(const short8*)&As[aoff[mi]];
#pragma unroll
    for (int ni = 0; ni < 4; ni++) bf[ni] = *(const short8*)&Bs[boff[ni]];
#pragma unroll
    for (int mi = 0; mi < 4; mi++)
#pragma unroll
      for (int ni = 0; ni < 4; ni++)
        acc[mi][ni] = MFMA16(af[mi], bf[ni], acc[mi][ni]);
  }

#pragma unroll
  for (int mi = 0; mi < 4; mi++) {
#pragma unroll
    for (int ni = 0; ni < 4; ni++) {
      const int gn = n0 + wn * 64 + ni * 16 + l16;
      const float bv = bf2f(bias[gn]);
      const int gm0 = m0 + wm * 64 + mi * 16 + quad * 4;
      if (z == 2) {
        const int bb = gm0 >> 9, ll0 = gm0 & 511;
        const int hh = gn >> 6, dd = gn & 63;
        ushort4 pk;
        pk.x = f2bf(clampf(acc[mi][ni][0] + bv, 1e4f));
        pk.y = f2bf(clampf(acc[mi][ni][1] + bv, 1e4f));
        pk.z = f2bf(clampf(acc[mi][ni][2] + bv, 1e4f));
        pk.w = f2bf(clampf(acc[mi][ni][3] + bv, 1e4f));
        *(ushort4*)&vt[(((size_t)(bb * NH_ + hh)) * D_ + dd) * L_ + ll0] = pk;
      } else {
#pragma unroll
        for (int r = 0; r < 4; r++) {
          const int gm = gm0 + r;
          const float fval = clampf(acc[mi][ni][r] + bv, 1e4f);
          uint16_t* O = out + (size_t)z * ((size_t)BH_ * L_ * D_);
          const int bb = gm >> 9, ll = gm & 511, hh = gn >> 6, dd = gn & 63;
          O[(((size_t)(bb * NH_ + hh)) * L_ + ll) * D_ + dd] = f2bf(fval);
        }
      }
    }
  }
}

// ---------------------------------------------------------------------------
// 64x64-tile out-projection GEMM, BK=64, fp32 output (validated R15).
// ---------------------------------------------------------------------------
__global__ __launch_bounds__(256) void gemm64o(
    const uint16_t* __restrict__ A, const uint16_t* __restrict__ BT,
    const uint16_t* __restrict__ bias, float* __restrict__ out) {
  __shared__ __align__(16) uint16_t As[64 * 64];
  __shared__ __align__(16) uint16_t Bs[64 * 64];

  const int tid = threadIdx.x;
  const int lane = tid & 63, quad = lane >> 4, l16 = lane & 15;
  const int w = tid >> 6, wm = w & 1, wn = w >> 1;
  const int m0 = blockIdx.x * 64, n0 = blockIdx.y * 64;

  fv4 acc[2][2];
#pragma unroll
  for (int i = 0; i < 2; i++)
#pragma unroll
    for (int j = 0; j < 2; j++) acc[i][j] = (fv4){0.f, 0.f, 0.f, 0.f};

  const int c0 = tid, c1 = tid + 256;
  const int r0 = c0 >> 3, g0 = (c0 & 7) ^ (r0 & 7);
  const int r1 = c1 >> 3, g1 = (c1 & 7) ^ (r1 & 7);
  const uint16_t* A0 = A + (size_t)(m0 + r0) * HID_ + g0 * 8;
  const uint16_t* A1 = A + (size_t)(m0 + r1) * HID_ + g1 * 8;
  const uint16_t* B0 = BT + (size_t)(n0 + r0) * HID_ + g0 * 8;
  const uint16_t* B1 = BT + (size_t)(n0 + r1) * HID_ + g1 * 8;
  uint16_t* lA0 = &As[c0 * 8];
  uint16_t* lA1 = &As[c1 * 8];
  uint16_t* lB0 = &Bs[c0 * 8];
  uint16_t* lB1 = &Bs[c1 * 8];

  int aoff[2][2], boff[2][2];
#pragma unroll
  for (int mi = 0; mi < 2; mi++) {
    const int row = wm * 32 + mi * 16 + l16;
#pragma unroll
    for (int kc = 0; kc < 2; kc++)
      aoff[mi][kc] = row * 64 + ((kc * 4 + quad) ^ (row & 7)) * 8;
  }
#pragma unroll
  for (int ni = 0; ni < 2; ni++) {
    const int row = wn * 32 + ni * 16 + l16;
#pragma unroll
    for (int kc = 0; kc < 2; kc++)
      boff[ni][kc] = row * 64 + ((kc * 4 + quad) ^ (row & 7)) * 8;
  }

  for (int k0 = 0; k0 < HID_; k0 += 64) {
    __syncthreads();
    gld_lds16(A0 + k0, lA0);
    gld_lds16(A1 + k0, lA1);
    gld_lds16(B0 + k0, lB0);
    gld_lds16(B1 + k0, lB1);
    __syncthreads();
#pragma unroll
    for (int kc = 0; kc < 2; kc++) {
      short8 af[2], bf[2];
#pragma unroll
      for (int mi = 0; mi < 2; mi++) af[mi] = *(const short8*)&As[aoff[mi][kc]];
#pragma unroll
      for (int ni = 0; ni < 2; ni++) bf[ni] = *(const short8*)&Bs[boff[ni][kc]];
#pragma unroll
      for (int mi = 0; mi < 2; mi++)
#pragma unroll
        for (int ni = 0; ni < 2; ni++)
          acc[mi][ni] = MFMA16(af[mi], bf[ni], acc[mi][ni]);
    }
  }

#pragma unroll
  for (int mi = 0; mi < 2; mi++) {
#pragma unroll
    for (int ni = 0; ni < 2; ni++) {
      const int gn = n0 + wn * 32 + ni * 16 + l16;
      const float bv = bf2f(bias[gn]);
#pragma unroll
      for (int r = 0; r < 4; r++) {
        const int gm = m0 + wm * 32 + mi * 16 + quad * 4 + r;
        out[(size_t)gm * HID_ + gn] = clampf(acc[mi][ni][r] + bv, 1e4f);
      }
    }
  }
}

// ---------------------------------------------------------------------------
// Fused attention v10.1 (R15-R17-validated; jc<7 prefetch guard kept).
// ---------------------------------------------------------------------------
#define SCALE_FX 4194304.f       // 2^22
#define INV_SCALE_FX 2.38418579e-7f
#define UBC 40.f                 // QK upper-bound margin

__global__ __launch_bounds__(256, 3) void attn_kernel(
    const uint16_t* __restrict__ Q, const uint16_t* __restrict__ Km,
    const uint16_t* __restrict__ Vt,
    const uint16_t* __restrict__ qh, const uint16_t* __restrict__ qe,
    const uint16_t* __restrict__ kh, const uint16_t* __restrict__ ke,
    const uint16_t* __restrict__ VET, const uint16_t* __restrict__ PKs,
    uint16_t* __restrict__ AO) {
  const int n = blockIdx.x;
  const int h = n % NH_;
  const int t2 = n / NH_;
  const int it = t2 & 7, b = t2 >> 3;
  const int bh = b * NH_ + h;
  const int tid = threadIdx.x;
  const int w = tid >> 6, lane = tid & 63, quad = lane >> 4, l16 = lane & 15;
  const int gi = it * 64 + w * 16;  // this wave's first query row

  __shared__ uint16_t cbs[4][16][98];               // bf16 bias projections
  __shared__ unsigned bkt[4][16][97];               // fixed-point buckets
  __shared__ __align__(16) uint16_t Pw[4][16][72];  // bf16 P chunk

  for (int k = lane; k < 16 * 97; k += 64)
    (&bkt[0][0][0])[w * 16 * 97 + k] = 0u;

  const size_t qkb = (size_t)bh * (L_ * D_);
  short8 a0 = *(const short8*)&Q[qkb + (size_t)(gi + l16) * D_ + quad * 8];
  short8 a1 = *(const short8*)&Q[qkb + (size_t)(gi + l16) * D_ + 32 + quad * 8];
  short8 kq0 = *(const short8*)&Km[qkb + (size_t)(gi + l16) * D_ + quad * 8];
  short8 kq1 =
      *(const short8*)&Km[qkb + (size_t)(gi + l16) * D_ + 32 + quad * 8];

  // ---- Cb via MFMA (R6-validated); per-row hop/edge maxes for free ----
  float hx[4] = {-1e30f, -1e30f, -1e30f, -1e30f};
  float ex[4] = {-1e30f, -1e30f, -1e30f, -1e30f};
#pragma unroll
  for (int nt = 0; nt < 6; nt++) {
    const uint16_t* eq;
    const uint16_t* ek;
    int t;
    if (nt < 2) { eq = qh; ek = kh; t = nt * 16 + l16; }
    else        { eq = qe; ek = ke; t = (nt - 2) * 16 + l16; }
    const size_t eb0 = (size_t)t * HID_ + h * D_;
    short8 bq0 = *(const short8*)&eq[eb0 + quad * 8];
    short8 bq1 = *(const short8*)&eq[eb0 + 32 + quad * 8];
    short8 bk0 = *(const short8*)&ek[eb0 + quad * 8];
    short8 bk1 = *(const short8*)&ek[eb0 + 32 + quad * 8];
    fv4 cc = (fv4){0.f, 0.f, 0.f, 0.f};
    cc = MFMA16(a0, bq0, cc);
    cc = MFMA16(a1, bq1, cc);
    cc = MFMA16(kq0, bk0, cc);
    cc = MFMA16(kq1, bk1, cc);
#pragma unroll
    for (int r = 0; r < 4; r++) {
      const float cv = clampf(cc[r], 1e4f);
      cbs[w][quad * 4 + r][nt * 16 + l16] = f2bf(cv);
      if (nt < 2) hx[r] = fmaxf(hx[r], cv);
      else        ex[r] = fmaxf(ex[r], cv);
    }
  }

  // UB per row: hop and edge maxes reduced separately, then added.
  float mx[4];
#pragma unroll
  for (int r = 0; r < 4; r++) {
    float mh = hx[r], me = ex[r];
    mh = fmaxf(mh, __shfl_xor(mh, 1, 16));
    mh = fmaxf(mh, __shfl_xor(mh, 2, 16));
    mh = fmaxf(mh, __shfl_xor(mh, 4, 16));
    mh = fmaxf(mh, __shfl_xor(mh, 8, 16));
    me = fmaxf(me, __shfl_xor(me, 1, 16));
    me = fmaxf(me, __shfl_xor(me, 2, 16));
    me = fmaxf(me, __shfl_xor(me, 4, 16));
    me = fmaxf(me, __shfl_xor(me, 8, 16));
    mx[r] = mh + me + UBC;
  }

  const uint16_t* pkw =
      PKs + (((size_t)(b * 8 + it) * 4 + w) * 8) * (64 * 16);
  const size_t vtb = (size_t)bh * (D_ * L_);

  fv4 oacc[4];
#pragma unroll
  for (int ni = 0; ni < 4; ni++) oacc[ni] = (fv4){0.f, 0.f, 0.f, 0.f};
  float lsr[4] = {0.f, 0.f, 0.f, 0.f};

  // preload jc=0 K-fragments + idx
  short8 ckb0[4], ckb1[4];
#pragma unroll
  for (int ni = 0; ni < 4; ni++) {
    const int key = ni * 16 + l16;
    ckb0[ni] = *(const short8*)&Km[qkb + (size_t)key * D_ + quad * 8];
    ckb1[ni] = *(const short8*)&Km[qkb + (size_t)key * D_ + 32 + quad * 8];
  }
  short8 cpk0 = *(const short8*)&pkw[lane * 16];
  short8 cpk1 = *(const short8*)&pkw[lane * 16 + 8];

  for (int jc = 0; jc < 8; jc++) {
    short8 nkb0[4], nkb1[4], npk0, npk1;
    if (jc < 7) {
      const int jn = jc + 1;
#pragma unroll
      for (int ni = 0; ni < 4; ni++) {
        const int key = jn * 64 + ni * 16 + l16;
        nkb0[ni] = *(const short8*)&Km[qkb + (size_t)key * D_ + quad * 8];
        nkb1[ni] = *(const short8*)&Km[qkb + (size_t)key * D_ + 32 + quad * 8];
      }
      npk0 = *(const short8*)&pkw[jn * 1024 + lane * 16];
      npk1 = *(const short8*)&pkw[jn * 1024 + lane * 16 + 8];
    }

    fv4 sacc[4];
#pragma unroll
    for (int ni = 0; ni < 4; ni++) {
      fv4 a = (fv4){0.f, 0.f, 0.f, 0.f};
      a = MFMA16(a0, ckb0[ni], a);
      sacc[ni] = MFMA16(a1, ckb1[ni], a);
    }

    int thv[16], tev[16];
#pragma unroll
    for (int k = 0; k < 16; k++) {
      const uint32_t pk = (uint16_t)((k < 8) ? cpk0[k] : cpk1[k - 8]);
      thv[k] = pk & 31;
      tev[k] = (pk >> 8) & 63;
    }
    float bsum[16];
#pragma unroll
    for (int k = 0; k < 16; k++) {
      const int row = quad * 4 + (k >> 2);
      bsum[k] = bf2f(cbs[w][row][thv[k]]) + bf2f(cbs[w][row][32 + tev[k]]);
    }
    float pv[16];
#pragma unroll
    for (int k = 0; k < 16; k++) {
      const int r = k >> 2;
      const float s = sacc[k & 3][r] + bsum[k];
      const float p = __expf((s - mx[r]) * 0.125f);
      pv[k] = p;
      lsr[r] += p;
    }
#pragma unroll
    for (int k = 0; k < 16; k++) {
      const int row = quad * 4 + (k >> 2);
      const unsigned pfx = (unsigned)(pv[k] * SCALE_FX + 0.5f);
      atomicAdd(&bkt[w][row][thv[k]], pfx);
      atomicAdd(&bkt[w][row][32 + tev[k]], pfx);
      Pw[w][row][(k & 3) * 16 + l16] = f2bf(pv[k]);
    }

#pragma unroll
    for (int kc = 0; kc < 2; kc++) {
      short8 pa = *(const short8*)&Pw[w][l16][kc * 32 + quad * 8];
#pragma unroll
      for (int ni = 0; ni < 4; ni++) {
        short8 vb = *(const short8*)&Vt[vtb + (size_t)(ni * 16 + l16) * L_ +
                                        jc * 64 + kc * 32 + quad * 8];
        oacc[ni] = MFMA16(pa, vb, oacc[ni]);
      }
    }

    if (jc < 7) {
#pragma unroll
      for (int ni = 0; ni < 4; ni++) {
        ckb0[ni] = nkb0[ni];
        ckb1[ni] = nkb1[ni];
      }
      cpk0 = npk0;
      cpk1 = npk1;
    }
  }

  // ---- E = bkt x VET (same C-layout as oacc; R9-R17-validated) ----
  const uint16_t* vet = VET + (size_t)h * D_ * TT_;
#pragma unroll
  for (int kc = 0; kc < 3; kc++) {
    short8 pa;
#pragma unroll
    for (int j = 0; j < 8; j++)
      pa[j] = (short)f2bf((float)bkt[w][l16][kc * 32 + quad * 8 + j] *
                          INV_SCALE_FX);
#pragma unroll
    for (int ni = 0; ni < 4; ni++) {
      short8 vb =
          *(const short8*)&vet[(size_t)(ni * 16 + l16) * TT_ + kc * 32 +
                               quad * 8];
      oacc[ni] = MFMA16(pa, vb, oacc[ni]);
    }
  }

  // ---- register l-normalize ----
  float linv[4];
#pragma unroll
  for (int r = 0; r < 4; r++) {
    float s = lsr[r];
    s += __shfl_xor(s, 1, 16);
    s += __shfl_xor(s, 2, 16);
    s += __shfl_xor(s, 4, 16);
    s += __shfl_xor(s, 8, 16);
    linv[r] = 1.f / s;
  }

#pragma unroll
  for (int ni = 0; ni < 4; ni++)
#pragma unroll
    for (int r = 0; r < 4; r++) {
      const int i = gi + quad * 4 + r;
      AO[(((size_t)b * L_ + i) * NH_ + h) * D_ + ni * 16 + l16] =
          f2bf(oacc[ni][r] * linv[r]);
    }
}

// ---------------------------------------------------------------------------
extern "C" void kernel_launch(void* const* d_in, const int* in_sizes, int n_in,
                              void* d_out, int out_size, void* d_ws,
                              size_t ws_size, hipStream_t stream) {
  const void* x_raw = d_in[0];
  const int* hop    = (const int*)d_in[7];
  const int* edge   = (const int*)d_in[8];

  char* ws = (char*)d_ws;
  uint16_t* QKV = (uint16_t*)(ws);                    // Q,K bf16 [B,NH,L,D]
  uint16_t* Qp  = QKV;
  uint16_t* Kp  = QKV + (size_t)BH_ * L_ * D_;
  uint16_t* Vtp = (uint16_t*)(ws + 18874368);         // [B,NH,D,L] bf16
  uint16_t* PKs = (uint16_t*)(ws + 25165824);         // swizzled idx u16
  uint16_t* AO  = (uint16_t*)(ws + 44040192);         // [B,L,NH,D] bf16
  uint16_t* WTq = (uint16_t*)(ws + 50331648);
  uint16_t* WTk = WTq + 768 * 768;
  uint16_t* WTv = WTk + 768 * 768;
  uint16_t* WTo = WTv + 768 * 768;
  uint16_t* CAN = (uint16_t*)(ws + 55050240);         // canonical bf16 inputs
  uint16_t* VET = (uint16_t*)(ws + 61790208);         // [NH,D,96] bf16

  uint16_t* xc  = CAN + SEG_X;
  uint16_t* qhc = CAN + SEG_QH;
  uint16_t* qec = CAN + SEG_QE;
  uint16_t* khc = CAN + SEG_KH;
  uint16_t* kec = CAN + SEG_KE;
  uint16_t* bqc = CAN + SEG_BQ;
  uint16_t* bkc = CAN + SEG_BK;
  uint16_t* bvc = CAN + SEG_BV;
  uint16_t* boc = CAN + SEG_BO;

  prep_all<<<PREP_ALL, 256, 0, stream>>>(
      x_raw, d_in[1], d_in[2], d_in[3], d_in[4], d_in[5], d_in[6],
      d_in[10], d_in[12], d_in[14], d_in[16],
      d_in[9], d_in[11], d_in[13], d_in[15],
      hop, edge, CAN, VET, PKs, WTq);

  gemm128<<<dim3(32, 6, 3), 256, 0, stream>>>(xc, WTq, WTk, WTv, bqc, bkc,
                                              bvc, QKV, Vtp);

  attn_kernel<<<768, 256, 0, stream>>>(Qp, Kp, Vtp, qhc, qec, khc, kec, VET,
                                       PKs, AO);

  gemm64o<<<dim3(64, 12), 256, 0, stream>>>(AO, WTo, boc, (float*)d_out);
}